// Round 6
// baseline (4126.941 us; speedup 1.0000x reference)
//
#include <hip/hip_runtime.h>
#include <hip/hip_bf16.h>

#define DIM 32
#define BSHIFT 8            // 256 rows per bucket
#define BROWS 256
#define CAP 12288           // bsort LDS capacity (mean 8192 edges/bucket, 45-sigma margin)
#define CHUNK 8192          // edges per bin block
#define KMAX 1024           // max buckets supported (N <= 262144)
#define CBINS 128           // col-sort bins per bucket

// ---------------- bucket build ----------------

// Per-bucket edge counts (bucket = row >> BSHIFT).
__global__ void lgcn_bhist(const int* __restrict__ row,
                           int* __restrict__ bcount, int E, int K) {
    __shared__ int h[KMAX];
    int t = threadIdx.x;
    for (int b = t; b < K; b += blockDim.x) h[b] = 0;
    __syncthreads();
    for (int i = blockIdx.x * blockDim.x + t; i < E; i += gridDim.x * blockDim.x)
        atomicAdd(&h[row[i] >> BSHIFT], 1);
    __syncthreads();
    for (int b = t; b < K; b += blockDim.x)
        if (h[b]) atomicAdd(&bcount[b], h[b]);
}

// Exclusive scan of bucket counts -> bbase[0..K], and bcursor = bbase copy.
__global__ void lgcn_bscan(const int* __restrict__ bcount,
                           int* __restrict__ bbase, int* __restrict__ bcursor, int K) {
    __shared__ int s[1024];
    int t = threadIdx.x;
    int v = (t < K) ? bcount[t] : 0;
    s[t] = v;
    __syncthreads();
    for (int off = 1; off < 1024; off <<= 1) {
        int u = (t >= off) ? s[t - off] : 0;
        __syncthreads();
        s[t] += u;
        __syncthreads();
    }
    if (t < K) {
        int excl = s[t] - v;
        bbase[t] = excl;
        bcursor[t] = excl;
    }
    if (t == 0) bbase[K] = s[1023];
}

// Bin edges into bucket-clustered order, LDS-sorted per chunk so global writes
// are issued contiguous-in-time per bucket segment (full-line writebacks).
// Packs rowlow into cv.x's top byte (requires N < 2^24).
__launch_bounds__(1024)
__global__ void lgcn_bin(const int* __restrict__ row, const int* __restrict__ col,
                         const float* __restrict__ vals, int* __restrict__ bcursor,
                         int2* __restrict__ binned, int E, int K) {
    __shared__ int hh[KMAX];       // count -> gdelta (gbase - local_excl_base)
    __shared__ int lb[KMAX + 1];   // scan buffer -> local exclusive bases
    __shared__ int cur[KMAX];      // LDS scatter cursors
    __shared__ int2 sbuf[CHUNK];   // 64 KB bucket-sorted chunk
    int t = threadIdx.x;
    int base = blockIdx.x * CHUNK;
    int cnt = E - base;
    if (cnt > CHUNK) cnt = CHUNK;

    for (int b = t; b < K; b += 1024) hh[b] = 0;
    __syncthreads();

    int  myb[CHUNK / 1024];
    int2 mycv[CHUNK / 1024];
    for (int k = 0; k < CHUNK / 1024; ++k) {
        int i = base + k * 1024 + t;
        if (i < base + cnt) {
            int r = row[i];
            myb[k] = r >> BSHIFT;
            mycv[k] = make_int2(col[i] | ((r & (BROWS - 1)) << 24),
                                __float_as_int(vals[i]));
            atomicAdd(&hh[myb[k]], 1);
        } else myb[k] = -1;
    }
    __syncthreads();

    // inclusive scan of hh over 1024 slots (hh[b>=K] == 0)
    int v = (t < K) ? hh[t] : 0;
    lb[t] = v;
    __syncthreads();
    for (int off = 1; off < 1024; off <<= 1) {
        int u = (t >= off) ? lb[t - off] : 0;
        __syncthreads();
        lb[t] += u;
        __syncthreads();
    }
    if (t == 0) lb[K] = cnt;
    int excl = lb[t] - v;          // local exclusive base for bucket t
    __syncthreads();
    if (t < K) {
        lb[t] = excl;
        cur[t] = excl;
        int gbase = v ? atomicAdd(&bcursor[t], v) : 0;
        hh[t] = gbase - excl;      // gdelta
    }
    __syncthreads();

    // scatter into LDS bucket-sorted order
    for (int k = 0; k < CHUNK / 1024; ++k) {
        if (myb[k] >= 0) {
            int pos = atomicAdd(&cur[myb[k]], 1);
            sbuf[pos] = mycv[k];
        }
    }
    __syncthreads();

    // ordered write-out: consecutive p -> consecutive global within each segment
    for (int p = t; p < cnt; p += 1024) {
        int lo = 0, hi = K;        // invariant: lb[lo] <= p < lb[hi]
        while (hi - lo > 1) {
            int mid = (lo + hi) >> 1;
            if (lb[mid] <= p) lo = mid; else hi = mid;
        }
        binned[hh[lo] + p] = sbuf[p];
    }
}

// Per-bucket LDS counting sort by COL window (in place). Key = col >> cshift
// (2048-col granularity): all pull blocks then sweep col-space in the same
// order, giving cross-block temporal L2 locality. rowlow stays packed.
__global__ void lgcn_bsort(const int* __restrict__ bbase,
                           int2* __restrict__ perm, int cshift) {
    __shared__ int2 sorted[CAP];
    __shared__ int cnt[CBINS], scn[CBINS], cur[CBINS];
    int b = blockIdx.x, t = threadIdx.x;
    int sB = bbase[b], eB = bbase[b + 1];
    int nB = eB - sB;
    if (t < CBINS) cnt[t] = 0;
    __syncthreads();
    for (int i = sB + t; i < eB; i += 1024)
        atomicAdd(&cnt[(perm[i].x & 0x00FFFFFF) >> cshift], 1);
    __syncthreads();
    if (t < CBINS) scn[t] = cnt[t];
    __syncthreads();
    for (int off = 1; off < CBINS; off <<= 1) {
        int u = (t >= off && t < CBINS) ? scn[t - off] : 0;
        __syncthreads();
        if (t < CBINS) scn[t] += u;
        __syncthreads();
    }
    if (t < CBINS) cur[t] = scn[t] - cnt[t];
    __syncthreads();
    for (int i = sB + t; i < eB; i += 1024) {
        int2 cv = perm[i];
        int bin = (cv.x & 0x00FFFFFF) >> cshift;
        int p = atomicAdd(&cur[bin], 1);
        if (p < CAP) sorted[p] = cv;
    }
    __syncthreads();
    for (int p = t; p < nB; p += 1024) {
        int pp = p < CAP ? p : CAP - 1;                  // unreachable clamp
        perm[sB + p] = sorted[pp];
    }
}

// ---------------- bucket-resident pull: LDS accumulators, col-sorted edges ----
// One block per 256-row bucket; all K blocks co-resident (4/CU) so every block
// sweeps col-space in lockstep-ish -> gather working set stays L2-sized.
// MODE 0: e_next = acc; out = emb + acc    (layer 1)
// MODE 1: e_next = acc; out += acc         (layer 2)
// MODE 2: out = (out + acc) * 0.25         (layer 3)
template <int MODE>
__launch_bounds__(256, 4)
__global__ void lgcn_pull(const int* __restrict__ bbase,
                          const int2* __restrict__ perm,
                          const float* __restrict__ e_cur,
                          float* __restrict__ e_next,
                          const float* __restrict__ emb,
                          float* __restrict__ out, int N) {
    __shared__ float acc[BROWS * DIM];                  // 32 KB
    int b = blockIdx.x, t = threadIdx.x;
    for (int i = t; i < BROWS * DIM / 4; i += 256)
        ((float4*)acc)[i] = make_float4(0.f, 0.f, 0.f, 0.f);
    __syncthreads();

    int sB = bbase[b], eB = bbase[b + 1];
    int d = t & 31;
    int g = t >> 5;                                     // 8 groups of 32 lanes
    int p = sB + g;
    for (; p + 24 < eB; p += 32) {                      // 4 edges in flight/group
        int2 c0 = perm[p];
        int2 c1 = perm[p + 8];
        int2 c2 = perm[p + 16];
        int2 c3 = perm[p + 24];
        float x0 = e_cur[(size_t)(c0.x & 0x00FFFFFF) * DIM + d];
        float x1 = e_cur[(size_t)(c1.x & 0x00FFFFFF) * DIM + d];
        float x2 = e_cur[(size_t)(c2.x & 0x00FFFFFF) * DIM + d];
        float x3 = e_cur[(size_t)(c3.x & 0x00FFFFFF) * DIM + d];
        atomicAdd(&acc[(((unsigned)c0.x >> 24) << 5) + d], __int_as_float(c0.y) * x0);
        atomicAdd(&acc[(((unsigned)c1.x >> 24) << 5) + d], __int_as_float(c1.y) * x1);
        atomicAdd(&acc[(((unsigned)c2.x >> 24) << 5) + d], __int_as_float(c2.y) * x2);
        atomicAdd(&acc[(((unsigned)c3.x >> 24) << 5) + d], __int_as_float(c3.y) * x3);
    }
    for (; p < eB; p += 8) {
        int2 cv = perm[p];
        float x = e_cur[(size_t)(cv.x & 0x00FFFFFF) * DIM + d];
        atomicAdd(&acc[(((unsigned)cv.x >> 24) << 5) + d], __int_as_float(cv.y) * x);
    }
    __syncthreads();

    int g0 = b << BSHIFT;
    int rows = N - g0; if (rows > BROWS) rows = BROWS;
    for (int i = t; i < rows * DIM; i += 256) {
        size_t o = (size_t)g0 * DIM + i;
        float a = acc[i];
        if (MODE == 0)      { e_next[o] = a; out[o] = emb[o] + a; }
        else if (MODE == 1) { e_next[o] = a; out[o] += a; }
        else                { out[o] = (out[o] + a) * 0.25f; }
    }
}

// ---------------- fallback (round-1 verified atomic path) ----------------

__global__ void lgcn_scatter(const float* __restrict__ e_cur,
                             float* __restrict__ e_next,
                             const float* __restrict__ vals,
                             const int* __restrict__ row_idx,
                             const int* __restrict__ col_idx, int E) {
    int g = blockIdx.x * (blockDim.x >> 5) + (threadIdx.x >> 5);
    if (g >= E) return;
    int d = threadIdx.x & 31;
    int c = col_idx[g];
    int r = row_idx[g];
    float v = vals[g];
    atomicAdd(&e_next[(size_t)r * DIM + d], v * e_cur[(size_t)c * DIM + d]);
}

__global__ void lgcn_add_init(const float* __restrict__ a, const float* __restrict__ b,
                              float* __restrict__ out, int n4) {
    int i = blockIdx.x * blockDim.x + threadIdx.x;
    if (i >= n4) return;
    float4 x = ((const float4*)a)[i]; float4 y = ((const float4*)b)[i];
    ((float4*)out)[i] = make_float4(x.x + y.x, x.y + y.y, x.z + y.z, x.w + y.w);
}
__global__ void lgcn_add(const float* __restrict__ b, float* __restrict__ out, int n4) {
    int i = blockIdx.x * blockDim.x + threadIdx.x;
    if (i >= n4) return;
    float4 x = ((float4*)out)[i]; float4 y = ((const float4*)b)[i];
    ((float4*)out)[i] = make_float4(x.x + y.x, x.y + y.y, x.z + y.z, x.w + y.w);
}
__global__ void lgcn_add_scale(const float* __restrict__ b, float* __restrict__ out,
                               int n4, float s) {
    int i = blockIdx.x * blockDim.x + threadIdx.x;
    if (i >= n4) return;
    float4 x = ((float4*)out)[i]; float4 y = ((const float4*)b)[i];
    ((float4*)out)[i] = make_float4((x.x + y.x) * s, (x.y + y.y) * s,
                                    (x.z + y.z) * s, (x.w + y.w) * s);
}

extern "C" void kernel_launch(void* const* d_in, const int* in_sizes, int n_in,
                              void* d_out, int out_size, void* d_ws, size_t ws_size,
                              hipStream_t stream) {
    const float* emb  = (const float*)d_in[0];
    const float* vals = (const float*)d_in[1];
    const int*   row  = (const int*)d_in[2];
    const int*   col  = (const int*)d_in[3];
    // num_layers (d_in[4]) fixed at 3 in the reference.

    const int N = in_sizes[0] / DIM;     // 200000
    const int E = in_sizes[1];           // 6.4M
    float* out  = (float*)d_out;

    const int K = (N + BROWS - 1) >> BSHIFT;   // buckets

    // ws layout (4B words):
    //   bufA[N*DIM] | bufB[N*DIM] | bcount[K] | bbase[K+1] | bcursor[K]
    //   | (8B-align) perm[E] int2
    float* bufA    = (float*)d_ws;
    float* bufB    = bufA + (size_t)N * DIM;
    int*   bcount  = (int*)(bufB + (size_t)N * DIM);
    int*   bbase   = bcount + K;
    int*   bcursor = bbase + (K + 1);
    size_t word_off = (size_t)((bcursor + K) - (int*)d_ws);
    word_off = (word_off + 1) & ~(size_t)1;            // 8B align
    int2*  perm    = (int2*)((int*)d_ws + word_off);
    const size_t needed = (word_off + (size_t)2 * E) * 4;

    const int n4 = N * DIM / 4;
    const int add_grid = (n4 + 255) / 256;
    const size_t layer_bytes = (size_t)N * DIM * sizeof(float);

    // col-sort shift: (N-1) >> cshift must fit in CBINS bins
    int cshift = 0;
    while (((N - 1) >> cshift) >= CBINS) ++cshift;

    // CSR path requires: ws fits, K fits LDS tables, bucket load margin,
    // col fits 24 bits for rowlow packing.
    const double mean_bucket = (double)E / (double)N * BROWS;
    const bool csr_ok = (ws_size >= needed) && (K <= KMAX) &&
                        (mean_bucket * 1.45 < (double)CAP) &&
                        (N < (1 << 24));

    if (!csr_ok) {
        // fallback: round-1 verified atomic push path
        const int sct_grid = (E + 7) / 8;
        hipMemsetAsync(bufA, 0, layer_bytes, stream);
        lgcn_scatter<<<sct_grid, 256, 0, stream>>>(emb, bufA, vals, row, col, E);
        lgcn_add_init<<<add_grid, 256, 0, stream>>>(emb, bufA, out, n4);
        hipMemsetAsync(bufB, 0, layer_bytes, stream);
        lgcn_scatter<<<sct_grid, 256, 0, stream>>>(bufA, bufB, vals, row, col, E);
        lgcn_add<<<add_grid, 256, 0, stream>>>(bufB, out, n4);
        hipMemsetAsync(bufA, 0, layer_bytes, stream);
        lgcn_scatter<<<sct_grid, 256, 0, stream>>>(bufB, bufA, vals, row, col, E);
        lgcn_add_scale<<<add_grid, 256, 0, stream>>>(bufA, out, n4, 0.25f);
        return;
    }

    // ---- bucketed build: bucket-cluster, then col-sort within bucket ----
    const int bin_grid = (E + CHUNK - 1) / CHUNK;
    hipMemsetAsync(bcount, 0, (size_t)K * sizeof(int), stream);
    lgcn_bhist<<<bin_grid, 256, 0, stream>>>(row, bcount, E, K);
    lgcn_bscan<<<1, 1024, 0, stream>>>(bcount, bbase, bcursor, K);
    lgcn_bin<<<bin_grid, 1024, 0, stream>>>(row, col, vals, bcursor, perm, E, K);
    lgcn_bsort<<<K, 1024, 0, stream>>>(bbase, perm, cshift);

    // ---- 3 bucket-resident pull layers ----
    lgcn_pull<0><<<K, 256, 0, stream>>>(bbase, perm, emb, bufA, emb, out, N);
    lgcn_pull<1><<<K, 256, 0, stream>>>(bbase, perm, bufA, bufB, emb, out, N);
    lgcn_pull<2><<<K, 256, 0, stream>>>(bbase, perm, bufB, nullptr, emb, out, N);
}

// Round 7
// 514.278 us; speedup vs baseline: 8.0247x; 8.0247x over previous
//
#include <hip/hip_runtime.h>
#include <hip/hip_bf16.h>

#define DIM 32
#define BSHIFT 8            // 256 rows per bucket
#define BROWS 256
#define CAP 12288           // bsort LDS capacity (mean 8192 edges/bucket, 45-sigma margin)
#define CHUNK 8192          // edges per bin block
#define KMAX 1024           // max buckets supported (N <= 262144)

// ---------------- bucket build ----------------

// Per-bucket edge counts (bucket = row >> BSHIFT).
__global__ void lgcn_bhist(const int* __restrict__ row,
                           int* __restrict__ bcount, int E, int K) {
    __shared__ int h[KMAX];
    int t = threadIdx.x;
    for (int b = t; b < K; b += blockDim.x) h[b] = 0;
    __syncthreads();
    for (int i = blockIdx.x * blockDim.x + t; i < E; i += gridDim.x * blockDim.x)
        atomicAdd(&h[row[i] >> BSHIFT], 1);
    __syncthreads();
    for (int b = t; b < K; b += blockDim.x)
        if (h[b]) atomicAdd(&bcount[b], h[b]);
}

// Exclusive scan of bucket counts -> bbase[0..K], and bcursor = bbase copy.
__global__ void lgcn_bscan(const int* __restrict__ bcount,
                           int* __restrict__ bbase, int* __restrict__ bcursor, int K) {
    __shared__ int s[1024];
    int t = threadIdx.x;
    int v = (t < K) ? bcount[t] : 0;
    s[t] = v;
    __syncthreads();
    for (int off = 1; off < 1024; off <<= 1) {
        int u = (t >= off) ? s[t - off] : 0;
        __syncthreads();
        s[t] += u;
        __syncthreads();
    }
    if (t < K) {
        int excl = s[t] - v;
        bbase[t] = excl;
        bcursor[t] = excl;
    }
    if (t == 0) bbase[K] = s[1023];
}

// Bin edges into bucket-clustered order, LDS-sorted per chunk so global writes
// are issued contiguous-in-time per bucket segment (full-line writebacks).
// Packs rowlow into cv.x's top byte (requires N < 2^24).
__launch_bounds__(1024)
__global__ void lgcn_bin(const int* __restrict__ row, const int* __restrict__ col,
                         const float* __restrict__ vals, int* __restrict__ bcursor,
                         int2* __restrict__ binned, int E, int K) {
    __shared__ int hh[KMAX];       // count -> gdelta (gbase - local_excl_base)
    __shared__ int lb[KMAX + 1];   // scan buffer -> local exclusive bases
    __shared__ int cur[KMAX];      // LDS scatter cursors
    __shared__ int2 sbuf[CHUNK];   // 64 KB bucket-sorted chunk
    int t = threadIdx.x;
    int base = blockIdx.x * CHUNK;
    int cnt = E - base;
    if (cnt > CHUNK) cnt = CHUNK;

    for (int b = t; b < K; b += 1024) hh[b] = 0;
    __syncthreads();

    int  myb[CHUNK / 1024];
    int2 mycv[CHUNK / 1024];
    for (int k = 0; k < CHUNK / 1024; ++k) {
        int i = base + k * 1024 + t;
        if (i < base + cnt) {
            int r = row[i];
            myb[k] = r >> BSHIFT;
            mycv[k] = make_int2(col[i] | ((r & (BROWS - 1)) << 24),
                                __float_as_int(vals[i]));
            atomicAdd(&hh[myb[k]], 1);
        } else myb[k] = -1;
    }
    __syncthreads();

    // inclusive scan of hh over 1024 slots (hh[b>=K] == 0)
    int v = (t < K) ? hh[t] : 0;
    lb[t] = v;
    __syncthreads();
    for (int off = 1; off < 1024; off <<= 1) {
        int u = (t >= off) ? lb[t - off] : 0;
        __syncthreads();
        lb[t] += u;
        __syncthreads();
    }
    if (t == 0) lb[K] = cnt;
    int excl = lb[t] - v;          // local exclusive base for bucket t
    __syncthreads();
    if (t < K) {
        lb[t] = excl;
        cur[t] = excl;
        int gbase = v ? atomicAdd(&bcursor[t], v) : 0;
        hh[t] = gbase - excl;      // gdelta
    }
    __syncthreads();

    // scatter into LDS bucket-sorted order
    for (int k = 0; k < CHUNK / 1024; ++k) {
        if (myb[k] >= 0) {
            int pos = atomicAdd(&cur[myb[k]], 1);
            sbuf[pos] = mycv[k];
        }
    }
    __syncthreads();

    // ordered write-out: consecutive p -> consecutive global within each segment
    for (int p = t; p < cnt; p += 1024) {
        int lo = 0, hi = K;        // invariant: lb[lo] <= p < lb[hi]
        while (hi - lo > 1) {
            int mid = (lo + hi) >> 1;
            if (lb[mid] <= p) lo = mid; else hi = mid;
        }
        binned[hh[lo] + p] = sbuf[p];
    }
}

// Per-bucket LDS counting sort (in place): binned -> row-sorted CSR segment.
// Strips the packed rowlow byte. Emits row_end[] (inclusive end offsets).
__global__ void lgcn_bsort(const int* __restrict__ bbase,
                           int2* __restrict__ perm,
                           int* __restrict__ row_end, int N) {
    __shared__ int2 sorted[CAP];
    __shared__ int cnt[BROWS], scn[BROWS], cur[BROWS];
    int b = blockIdx.x, t = threadIdx.x;
    int sB = bbase[b], eB = bbase[b + 1];
    int nB = eB - sB;
    if (t < BROWS) cnt[t] = 0;
    __syncthreads();
    for (int i = sB + t; i < eB; i += 1024)
        atomicAdd(&cnt[(unsigned)perm[i].x >> 24], 1);
    __syncthreads();
    if (t < BROWS) scn[t] = cnt[t];
    __syncthreads();
    for (int off = 1; off < BROWS; off <<= 1) {
        int u = (t >= off && t < BROWS) ? scn[t - off] : 0;
        __syncthreads();
        if (t < BROWS) scn[t] += u;
        __syncthreads();
    }
    int g0 = b << BSHIFT;
    if (t < BROWS) {
        if (g0 + t < N) row_end[g0 + t] = sB + scn[t];   // inclusive end
        cur[t] = scn[t] - cnt[t];                        // local exclusive start
    }
    __syncthreads();
    for (int i = sB + t; i < eB; i += 1024) {
        int2 cv = perm[i];
        int r = (unsigned)cv.x >> 24;
        int p = atomicAdd(&cur[r], 1);
        if (p < CAP) sorted[p] = cv;
    }
    __syncthreads();
    for (int p = t; p < nB; p += 1024) {
        int pp = p < CAP ? p : CAP - 1;                  // unreachable clamp
        int2 cv = sorted[pp];
        perm[sB + p] = make_int2(cv.x & 0x00FFFFFF, cv.y);
    }
}

// ---------------- pull SpMM, fused layer-sum epilogue ----------------
// One 32-lane group per row, 8 edges in flight (deep MLP: 8 uniform perm
// loads + 8 independent 128B gathers per iteration).
// MODE 0: e_next = acc; out = emb + acc    (layer 1)
// MODE 1: e_next = acc; out += acc         (layer 2)
// MODE 2: out = (out + acc) * 0.25         (layer 3)
template <int MODE>
__global__ void lgcn_pull(const int* __restrict__ row_end,
                          const int2* __restrict__ perm,
                          const float* __restrict__ e_cur,
                          float* __restrict__ e_next,
                          const float* __restrict__ emb,
                          float* __restrict__ out, int N) {
    int g = blockIdx.x * (blockDim.x >> 5) + (threadIdx.x >> 5);
    if (g >= N) return;
    int d = threadIdx.x & 31;
    int beg = (g == 0) ? 0 : row_end[g - 1];
    int end = row_end[g];
    float acc = 0.f;
    int p = beg;
    for (; p + 7 < end; p += 8) {
        int2 cv0 = perm[p];
        int2 cv1 = perm[p + 1];
        int2 cv2 = perm[p + 2];
        int2 cv3 = perm[p + 3];
        int2 cv4 = perm[p + 4];
        int2 cv5 = perm[p + 5];
        int2 cv6 = perm[p + 6];
        int2 cv7 = perm[p + 7];
        float x0 = e_cur[(size_t)cv0.x * DIM + d];
        float x1 = e_cur[(size_t)cv1.x * DIM + d];
        float x2 = e_cur[(size_t)cv2.x * DIM + d];
        float x3 = e_cur[(size_t)cv3.x * DIM + d];
        float x4 = e_cur[(size_t)cv4.x * DIM + d];
        float x5 = e_cur[(size_t)cv5.x * DIM + d];
        float x6 = e_cur[(size_t)cv6.x * DIM + d];
        float x7 = e_cur[(size_t)cv7.x * DIM + d];
        acc = fmaf(__int_as_float(cv0.y), x0, acc);
        acc = fmaf(__int_as_float(cv1.y), x1, acc);
        acc = fmaf(__int_as_float(cv2.y), x2, acc);
        acc = fmaf(__int_as_float(cv3.y), x3, acc);
        acc = fmaf(__int_as_float(cv4.y), x4, acc);
        acc = fmaf(__int_as_float(cv5.y), x5, acc);
        acc = fmaf(__int_as_float(cv6.y), x6, acc);
        acc = fmaf(__int_as_float(cv7.y), x7, acc);
    }
    for (; p < end; ++p) {
        int2 cv = perm[p];
        acc = fmaf(__int_as_float(cv.y), e_cur[(size_t)cv.x * DIM + d], acc);
    }
    size_t o = (size_t)g * DIM + d;
    if (MODE == 0)      { e_next[o] = acc; out[o] = emb[o] + acc; }
    else if (MODE == 1) { e_next[o] = acc; out[o] += acc; }
    else                { out[o] = (out[o] + acc) * 0.25f; }
}

// ---------------- fallback (round-1 verified atomic path) ----------------

__global__ void lgcn_scatter(const float* __restrict__ e_cur,
                             float* __restrict__ e_next,
                             const float* __restrict__ vals,
                             const int* __restrict__ row_idx,
                             const int* __restrict__ col_idx, int E) {
    int g = blockIdx.x * (blockDim.x >> 5) + (threadIdx.x >> 5);
    if (g >= E) return;
    int d = threadIdx.x & 31;
    int c = col_idx[g];
    int r = row_idx[g];
    float v = vals[g];
    atomicAdd(&e_next[(size_t)r * DIM + d], v * e_cur[(size_t)c * DIM + d]);
}

__global__ void lgcn_add_init(const float* __restrict__ a, const float* __restrict__ b,
                              float* __restrict__ out, int n4) {
    int i = blockIdx.x * blockDim.x + threadIdx.x;
    if (i >= n4) return;
    float4 x = ((const float4*)a)[i]; float4 y = ((const float4*)b)[i];
    ((float4*)out)[i] = make_float4(x.x + y.x, x.y + y.y, x.z + y.z, x.w + y.w);
}
__global__ void lgcn_add(const float* __restrict__ b, float* __restrict__ out, int n4) {
    int i = blockIdx.x * blockDim.x + threadIdx.x;
    if (i >= n4) return;
    float4 x = ((float4*)out)[i]; float4 y = ((const float4*)b)[i];
    ((float4*)out)[i] = make_float4(x.x + y.x, x.y + y.y, x.z + y.z, x.w + y.w);
}
__global__ void lgcn_add_scale(const float* __restrict__ b, float* __restrict__ out,
                               int n4, float s) {
    int i = blockIdx.x * blockDim.x + threadIdx.x;
    if (i >= n4) return;
    float4 x = ((float4*)out)[i]; float4 y = ((const float4*)b)[i];
    ((float4*)out)[i] = make_float4((x.x + y.x) * s, (x.y + y.y) * s,
                                    (x.z + y.z) * s, (x.w + y.w) * s);
}

extern "C" void kernel_launch(void* const* d_in, const int* in_sizes, int n_in,
                              void* d_out, int out_size, void* d_ws, size_t ws_size,
                              hipStream_t stream) {
    const float* emb  = (const float*)d_in[0];
    const float* vals = (const float*)d_in[1];
    const int*   row  = (const int*)d_in[2];
    const int*   col  = (const int*)d_in[3];
    // num_layers (d_in[4]) fixed at 3 in the reference.

    const int N = in_sizes[0] / DIM;     // 200000
    const int E = in_sizes[1];           // 6.4M
    float* out  = (float*)d_out;

    const int K = (N + BROWS - 1) >> BSHIFT;   // buckets

    // ws layout (4B words):
    //   bufA[N*DIM] | bufB[N*DIM] | row_end[N] | bcount[K] | bbase[K+1] | bcursor[K]
    //   | (8B-align) perm[E] int2
    float* bufA    = (float*)d_ws;
    float* bufB    = bufA + (size_t)N * DIM;
    int*   row_end = (int*)(bufB + (size_t)N * DIM);
    int*   bcount  = row_end + N;
    int*   bbase   = bcount + K;
    int*   bcursor = bbase + (K + 1);
    size_t word_off = (size_t)((bcursor + K) - (int*)d_ws);
    word_off = (word_off + 1) & ~(size_t)1;            // 8B align
    int2*  perm    = (int2*)((int*)d_ws + word_off);
    const size_t needed = (word_off + (size_t)2 * E) * 4;

    const int n4 = N * DIM / 4;
    const int add_grid = (n4 + 255) / 256;
    const size_t layer_bytes = (size_t)N * DIM * sizeof(float);

    // CSR path requires: ws fits, K fits LDS tables, bucket load margin,
    // col fits 24 bits for rowlow packing.
    const double mean_bucket = (double)E / (double)N * BROWS;
    const bool csr_ok = (ws_size >= needed) && (K <= KMAX) &&
                        (mean_bucket * 1.45 < (double)CAP) &&
                        (N < (1 << 24));

    if (!csr_ok) {
        // fallback: round-1 verified atomic push path
        const int sct_grid = (E + 7) / 8;
        hipMemsetAsync(bufA, 0, layer_bytes, stream);
        lgcn_scatter<<<sct_grid, 256, 0, stream>>>(emb, bufA, vals, row, col, E);
        lgcn_add_init<<<add_grid, 256, 0, stream>>>(emb, bufA, out, n4);
        hipMemsetAsync(bufB, 0, layer_bytes, stream);
        lgcn_scatter<<<sct_grid, 256, 0, stream>>>(bufA, bufB, vals, row, col, E);
        lgcn_add<<<add_grid, 256, 0, stream>>>(bufB, out, n4);
        hipMemsetAsync(bufA, 0, layer_bytes, stream);
        lgcn_scatter<<<sct_grid, 256, 0, stream>>>(bufB, bufA, vals, row, col, E);
        lgcn_add_scale<<<add_grid, 256, 0, stream>>>(bufA, out, n4, 0.25f);
        return;
    }

    // ---- bucketed CSR build ----
    const int bin_grid = (E + CHUNK - 1) / CHUNK;
    hipMemsetAsync(bcount, 0, (size_t)K * sizeof(int), stream);
    lgcn_bhist<<<bin_grid, 256, 0, stream>>>(row, bcount, E, K);
    lgcn_bscan<<<1, 1024, 0, stream>>>(bcount, bbase, bcursor, K);
    lgcn_bin<<<bin_grid, 1024, 0, stream>>>(row, col, vals, bcursor, perm, E, K);
    lgcn_bsort<<<K, 1024, 0, stream>>>(bbase, perm, row_end, N);

    // ---- 3 pull layers, fused accumulation ----
    const int pull_grid = (N + 7) / 8;
    lgcn_pull<0><<<pull_grid, 256, 0, stream>>>(row_end, perm, emb, bufA, emb, out, N);
    lgcn_pull<1><<<pull_grid, 256, 0, stream>>>(row_end, perm, bufA, bufB, emb, out, N);
    lgcn_pull<2><<<pull_grid, 256, 0, stream>>>(row_end, perm, bufB, nullptr, emb, out, N);
}

// Round 8
// 457.128 us; speedup vs baseline: 9.0280x; 1.1250x over previous
//
#include <hip/hip_runtime.h>
#include <hip/hip_bf16.h>
#include <hip/hip_fp16.h>

#define DIM 32
#define BSHIFT 8            // 256 rows per bucket
#define BROWS 256
#define CAP 12288           // bsort LDS capacity (mean 8192 edges/bucket, 45-sigma margin)
#define CHUNK 8192          // edges per bin block
#define KMAX 1024           // max buckets supported (N <= 262144)

// ---------------- bucket build ----------------

__global__ void lgcn_bhist(const int* __restrict__ row,
                           int* __restrict__ bcount, int E, int K) {
    __shared__ int h[KMAX];
    int t = threadIdx.x;
    for (int b = t; b < K; b += blockDim.x) h[b] = 0;
    __syncthreads();
    for (int i = blockIdx.x * blockDim.x + t; i < E; i += gridDim.x * blockDim.x)
        atomicAdd(&h[row[i] >> BSHIFT], 1);
    __syncthreads();
    for (int b = t; b < K; b += blockDim.x)
        if (h[b]) atomicAdd(&bcount[b], h[b]);
}

__global__ void lgcn_bscan(const int* __restrict__ bcount,
                           int* __restrict__ bbase, int* __restrict__ bcursor, int K) {
    __shared__ int s[1024];
    int t = threadIdx.x;
    int v = (t < K) ? bcount[t] : 0;
    s[t] = v;
    __syncthreads();
    for (int off = 1; off < 1024; off <<= 1) {
        int u = (t >= off) ? s[t - off] : 0;
        __syncthreads();
        s[t] += u;
        __syncthreads();
    }
    if (t < K) {
        int excl = s[t] - v;
        bbase[t] = excl;
        bcursor[t] = excl;
    }
    if (t == 0) bbase[K] = s[1023];
}

// Bin edges into bucket-clustered order, LDS-sorted per chunk so global writes
// are issued contiguous-in-time per bucket segment. Packs rowlow in top byte.
__launch_bounds__(1024)
__global__ void lgcn_bin(const int* __restrict__ row, const int* __restrict__ col,
                         const float* __restrict__ vals, int* __restrict__ bcursor,
                         int2* __restrict__ binned, int E, int K) {
    __shared__ int hh[KMAX];
    __shared__ int lb[KMAX + 1];
    __shared__ int cur[KMAX];
    __shared__ int2 sbuf[CHUNK];
    int t = threadIdx.x;
    int base = blockIdx.x * CHUNK;
    int cnt = E - base;
    if (cnt > CHUNK) cnt = CHUNK;

    for (int b = t; b < K; b += 1024) hh[b] = 0;
    __syncthreads();

    int  myb[CHUNK / 1024];
    int2 mycv[CHUNK / 1024];
    for (int k = 0; k < CHUNK / 1024; ++k) {
        int i = base + k * 1024 + t;
        if (i < base + cnt) {
            int r = row[i];
            myb[k] = r >> BSHIFT;
            mycv[k] = make_int2(col[i] | ((r & (BROWS - 1)) << 24),
                                __float_as_int(vals[i]));
            atomicAdd(&hh[myb[k]], 1);
        } else myb[k] = -1;
    }
    __syncthreads();

    int v = (t < K) ? hh[t] : 0;
    lb[t] = v;
    __syncthreads();
    for (int off = 1; off < 1024; off <<= 1) {
        int u = (t >= off) ? lb[t - off] : 0;
        __syncthreads();
        lb[t] += u;
        __syncthreads();
    }
    if (t == 0) lb[K] = cnt;
    int excl = lb[t] - v;
    __syncthreads();
    if (t < K) {
        lb[t] = excl;
        cur[t] = excl;
        int gbase = v ? atomicAdd(&bcursor[t], v) : 0;
        hh[t] = gbase - excl;
    }
    __syncthreads();

    for (int k = 0; k < CHUNK / 1024; ++k) {
        if (myb[k] >= 0) {
            int pos = atomicAdd(&cur[myb[k]], 1);
            sbuf[pos] = mycv[k];
        }
    }
    __syncthreads();

    for (int p = t; p < cnt; p += 1024) {
        int lo = 0, hi = K;
        while (hi - lo > 1) {
            int mid = (lo + hi) >> 1;
            if (lb[mid] <= p) lo = mid; else hi = mid;
        }
        binned[hh[lo] + p] = sbuf[p];
    }
}

// Per-bucket LDS counting sort (in place) -> row-sorted CSR; emits row_end[].
__global__ void lgcn_bsort(const int* __restrict__ bbase,
                           int2* __restrict__ perm,
                           int* __restrict__ row_end, int N) {
    __shared__ int2 sorted[CAP];
    __shared__ int cnt[BROWS], scn[BROWS], cur[BROWS];
    int b = blockIdx.x, t = threadIdx.x;
    int sB = bbase[b], eB = bbase[b + 1];
    int nB = eB - sB;
    if (t < BROWS) cnt[t] = 0;
    __syncthreads();
    for (int i = sB + t; i < eB; i += 1024)
        atomicAdd(&cnt[(unsigned)perm[i].x >> 24], 1);
    __syncthreads();
    if (t < BROWS) scn[t] = cnt[t];
    __syncthreads();
    for (int off = 1; off < BROWS; off <<= 1) {
        int u = (t >= off && t < BROWS) ? scn[t - off] : 0;
        __syncthreads();
        if (t < BROWS) scn[t] += u;
        __syncthreads();
    }
    int g0 = b << BSHIFT;
    if (t < BROWS) {
        if (g0 + t < N) row_end[g0 + t] = sB + scn[t];
        cur[t] = scn[t] - cnt[t];
    }
    __syncthreads();
    for (int i = sB + t; i < eB; i += 1024) {
        int2 cv = perm[i];
        int r = (unsigned)cv.x >> 24;
        int p = atomicAdd(&cur[r], 1);
        if (p < CAP) sorted[p] = cv;
    }
    __syncthreads();
    for (int p = t; p < nB; p += 1024) {
        int pp = p < CAP ? p : CAP - 1;
        int2 cv = sorted[pp];
        perm[sB + p] = make_int2(cv.x & 0x00FFFFFF, cv.y);
    }
}

// f32 -> f16 convert (for the gathered operand)
__global__ void lgcn_f2h(const float* __restrict__ src,
                         __half2* __restrict__ dst, int n2) {
    int i = blockIdx.x * blockDim.x + threadIdx.x;
    if (i >= n2) return;
    float2 v = ((const float2*)src)[i];
    dst[i] = __float22half2_rn(v);
}

// ---------------- pull SpMM, f16 gather (64B/row), f32 accumulate ----------------
// 32-lane group per row; lanes split: sub = lane>>4 handles even/odd edges,
// d2 = lane&15 owns dims {2*d2, 2*d2+1} as half2. 8 edges in flight per group.
// MODE 0: e_next = h(acc); out = emb + acc    (layer 1)
// MODE 1: e_next = h(acc); out += acc         (layer 2)
// MODE 2: out = (out + acc) * 0.25            (layer 3)
template <int MODE>
__global__ void lgcn_pull(const int* __restrict__ row_end,
                          const int2* __restrict__ perm,
                          const __half2* __restrict__ e_cur,
                          __half2* __restrict__ e_next,
                          const float* __restrict__ emb,
                          float* __restrict__ out, int N) {
    int g = blockIdx.x * (blockDim.x >> 5) + (threadIdx.x >> 5);
    if (g >= N) return;
    int l = threadIdx.x & 31;
    int sub = l >> 4;
    int d2 = l & 15;
    int beg = (g == 0) ? 0 : row_end[g - 1];
    int end = row_end[g];
    float ax = 0.f, ay = 0.f;
    int p = beg + sub;
    for (; p + 6 < end; p += 8) {
        int2 c0 = perm[p];
        int2 c1 = perm[p + 2];
        int2 c2 = perm[p + 4];
        int2 c3 = perm[p + 6];
        float2 x0 = __half22float2(e_cur[(size_t)c0.x * 16 + d2]);
        float2 x1 = __half22float2(e_cur[(size_t)c1.x * 16 + d2]);
        float2 x2 = __half22float2(e_cur[(size_t)c2.x * 16 + d2]);
        float2 x3 = __half22float2(e_cur[(size_t)c3.x * 16 + d2]);
        float v0 = __int_as_float(c0.y), v1 = __int_as_float(c1.y);
        float v2 = __int_as_float(c2.y), v3 = __int_as_float(c3.y);
        ax = fmaf(v0, x0.x, ax); ay = fmaf(v0, x0.y, ay);
        ax = fmaf(v1, x1.x, ax); ay = fmaf(v1, x1.y, ay);
        ax = fmaf(v2, x2.x, ax); ay = fmaf(v2, x2.y, ay);
        ax = fmaf(v3, x3.x, ax); ay = fmaf(v3, x3.y, ay);
    }
    for (; p < end; p += 2) {
        int2 cv = perm[p];
        float2 x = __half22float2(e_cur[(size_t)cv.x * 16 + d2]);
        float v = __int_as_float(cv.y);
        ax = fmaf(v, x.x, ax); ay = fmaf(v, x.y, ay);
    }
    ax += __shfl_xor(ax, 16);
    ay += __shfl_xor(ay, 16);
    if (sub == 0) {
        size_t o2 = (size_t)g * 16 + d2;
        if (MODE == 0) {
            e_next[o2] = __float22half2_rn(make_float2(ax, ay));
            float2 e0 = ((const float2*)emb)[o2];
            ((float2*)out)[o2] = make_float2(e0.x + ax, e0.y + ay);
        } else if (MODE == 1) {
            e_next[o2] = __float22half2_rn(make_float2(ax, ay));
            float2 c = ((float2*)out)[o2];
            ((float2*)out)[o2] = make_float2(c.x + ax, c.y + ay);
        } else {
            float2 c = ((float2*)out)[o2];
            ((float2*)out)[o2] = make_float2((c.x + ax) * 0.25f,
                                             (c.y + ay) * 0.25f);
        }
    }
}

// ---------------- fallback (round-1 verified atomic path) ----------------

__global__ void lgcn_scatter(const float* __restrict__ e_cur,
                             float* __restrict__ e_next,
                             const float* __restrict__ vals,
                             const int* __restrict__ row_idx,
                             const int* __restrict__ col_idx, int E) {
    int g = blockIdx.x * (blockDim.x >> 5) + (threadIdx.x >> 5);
    if (g >= E) return;
    int d = threadIdx.x & 31;
    int c = col_idx[g];
    int r = row_idx[g];
    float v = vals[g];
    atomicAdd(&e_next[(size_t)r * DIM + d], v * e_cur[(size_t)c * DIM + d]);
}

__global__ void lgcn_add_init(const float* __restrict__ a, const float* __restrict__ b,
                              float* __restrict__ out, int n4) {
    int i = blockIdx.x * blockDim.x + threadIdx.x;
    if (i >= n4) return;
    float4 x = ((const float4*)a)[i]; float4 y = ((const float4*)b)[i];
    ((float4*)out)[i] = make_float4(x.x + y.x, x.y + y.y, x.z + y.z, x.w + y.w);
}
__global__ void lgcn_add(const float* __restrict__ b, float* __restrict__ out, int n4) {
    int i = blockIdx.x * blockDim.x + threadIdx.x;
    if (i >= n4) return;
    float4 x = ((float4*)out)[i]; float4 y = ((const float4*)b)[i];
    ((float4*)out)[i] = make_float4(x.x + y.x, x.y + y.y, x.z + y.z, x.w + y.w);
}
__global__ void lgcn_add_scale(const float* __restrict__ b, float* __restrict__ out,
                               int n4, float s) {
    int i = blockIdx.x * blockDim.x + threadIdx.x;
    if (i >= n4) return;
    float4 x = ((float4*)out)[i]; float4 y = ((const float4*)b)[i];
    ((float4*)out)[i] = make_float4((x.x + y.x) * s, (x.y + y.y) * s,
                                    (x.z + y.z) * s, (x.w + y.w) * s);
}

extern "C" void kernel_launch(void* const* d_in, const int* in_sizes, int n_in,
                              void* d_out, int out_size, void* d_ws, size_t ws_size,
                              hipStream_t stream) {
    const float* emb  = (const float*)d_in[0];
    const float* vals = (const float*)d_in[1];
    const int*   row  = (const int*)d_in[2];
    const int*   col  = (const int*)d_in[3];
    // num_layers (d_in[4]) fixed at 3 in the reference.

    const int N = in_sizes[0] / DIM;     // 200000
    const int E = in_sizes[1];           // 6.4M
    float* out  = (float*)d_out;

    const int K = (N + BROWS - 1) >> BSHIFT;

    // ws layout (4B words):
    //   emb_h[N*DIM/2] | bufA_h[N*DIM/2] | bufB_h[N*DIM/2] | row_end[N]
    //   | bcount[K] | bbase[K+1] | bcursor[K] | (8B-align) perm[E] int2
    const size_t hwords = (size_t)N * DIM / 2;        // words per f16 layer buffer
    __half2* emb_h  = (__half2*)d_ws;
    __half2* bufA_h = (__half2*)((int*)d_ws + hwords);
    __half2* bufB_h = (__half2*)((int*)d_ws + 2 * hwords);
    int*   row_end = (int*)d_ws + 3 * hwords;
    int*   bcount  = row_end + N;
    int*   bbase   = bcount + K;
    int*   bcursor = bbase + (K + 1);
    size_t word_off = (size_t)((bcursor + K) - (int*)d_ws);
    word_off = (word_off + 1) & ~(size_t)1;           // 8B align
    int2*  perm    = (int2*)((int*)d_ws + word_off);
    const size_t needed = (word_off + (size_t)2 * E) * 4;

    const int n4 = N * DIM / 4;
    const int n2 = N * DIM / 2;
    const int add_grid = (n4 + 255) / 256;
    const size_t layer_bytes = (size_t)N * DIM * sizeof(float);

    const double mean_bucket = (double)E / (double)N * BROWS;
    const bool csr_ok = (ws_size >= needed) && (K <= KMAX) &&
                        (mean_bucket * 1.45 < (double)CAP) &&
                        (N < (1 << 24)) && (DIM % 4 == 0);

    if (!csr_ok) {
        // fallback: round-1 verified atomic push path (f32 buffers alias ws)
        float* bufA = (float*)d_ws;
        float* bufB = bufA + (size_t)N * DIM;
        const int sct_grid = (E + 7) / 8;
        hipMemsetAsync(bufA, 0, layer_bytes, stream);
        lgcn_scatter<<<sct_grid, 256, 0, stream>>>(emb, bufA, vals, row, col, E);
        lgcn_add_init<<<add_grid, 256, 0, stream>>>(emb, bufA, out, n4);
        hipMemsetAsync(bufB, 0, layer_bytes, stream);
        lgcn_scatter<<<sct_grid, 256, 0, stream>>>(bufA, bufB, vals, row, col, E);
        lgcn_add<<<add_grid, 256, 0, stream>>>(bufB, out, n4);
        hipMemsetAsync(bufA, 0, layer_bytes, stream);
        lgcn_scatter<<<sct_grid, 256, 0, stream>>>(bufB, bufA, vals, row, col, E);
        lgcn_add_scale<<<add_grid, 256, 0, stream>>>(bufA, out, n4, 0.25f);
        return;
    }

    // ---- bucketed CSR build + emb f16 convert ----
    const int bin_grid = (E + CHUNK - 1) / CHUNK;
    hipMemsetAsync(bcount, 0, (size_t)K * sizeof(int), stream);
    lgcn_f2h<<<(n2 + 255) / 256, 256, 0, stream>>>(emb, emb_h, n2);
    lgcn_bhist<<<bin_grid, 256, 0, stream>>>(row, bcount, E, K);
    lgcn_bscan<<<1, 1024, 0, stream>>>(bcount, bbase, bcursor, K);
    lgcn_bin<<<bin_grid, 1024, 0, stream>>>(row, col, vals, bcursor, perm, E, K);
    lgcn_bsort<<<K, 1024, 0, stream>>>(bbase, perm, row_end, N);

    // ---- 3 pull layers (f16 gather, f32 accumulate) ----
    const int pull_grid = (N + 7) / 8;
    lgcn_pull<0><<<pull_grid, 256, 0, stream>>>(row_end, perm, emb_h, bufA_h, emb, out, N);
    lgcn_pull<1><<<pull_grid, 256, 0, stream>>>(row_end, perm, bufA_h, bufB_h, emb, out, N);
    lgcn_pull<2><<<pull_grid, 256, 0, stream>>>(row_end, perm, bufB_h, nullptr, emb, out, N);
}